// Round 4
// baseline (13433.498 us; speedup 1.0000x reference)
//
#include <hip/hip_runtime.h>
#include <hip/hip_bf16.h>
#include <math.h>

#define Bc 256
#define Tc 256
#define Hc 512
#define INc 5
#define BH (Bc * Hc)
#define NB 256  // grid blocks == CU count: all blocks co-resident (1 block/CU, 4 waves)

typedef __bf16 bf16x8 __attribute__((ext_vector_type(8)));
typedef float f32x4 __attribute__((ext_vector_type(4)));

__device__ __forceinline__ float sigmoidf_(float x) {
    return 1.0f / (1.0f + __expf(-x));
}
__device__ __forceinline__ float tanhf_(float x) {
    float ax = fabsf(x);
    float e = __expf(2.0f * ax);
    float t = 1.0f - 2.0f / (e + 1.0f);
    return copysignf(t, x);
}
__device__ __forceinline__ unsigned short bfbits(float x) {  // RNE f32->bf16 bits
    unsigned int u = __builtin_bit_cast(unsigned int, x);
    unsigned int r = u + 0x7FFFu + ((u >> 16) & 1u);
    return (unsigned short)(r >> 16);
}

// Monotonic grid barrier: gen-th call waits until all NB blocks arrived gen times.
// Device-scope release add + acquire spin; __threadfence flushes h writes so
// other XCDs observe them after the acquire.
__device__ __forceinline__ void gbar(int* cnt, int gen, int tid) {
    __threadfence();
    __syncthreads();
    if (tid == 0) {
        __hip_atomic_fetch_add(cnt, 1, __ATOMIC_RELEASE, __HIP_MEMORY_SCOPE_AGENT);
        const int target = NB * gen;
        while (__hip_atomic_load(cnt, __ATOMIC_ACQUIRE, __HIP_MEMORY_SCOPE_AGENT) < target)
            __builtin_amdgcn_s_sleep(1);
    }
    __syncthreads();
}

// Blocks 0..127: layer0 (bb=bid>>4 batch-tile of 32, jb=bid&15 j-tile of 32).
// Blocks 128..255: layer1, same tiling, K=1024 (wcat1 = [w_hh1 | w_ih1] col-concat).
// Wave g = gate plane. W slices live in VGPRs for the whole kernel.
__global__ void __launch_bounds__(256, 1) lstm_persist(
    const float* __restrict__ x_time, const float* __restrict__ w_ih0,
    const float* __restrict__ b0v, const float* __restrict__ b1v,
    const float* __restrict__ fc1_w, const float* __restrict__ fc1_b,
    const float* __restrict__ x_stat,
    const float* __restrict__ fc2_w, const float* __restrict__ fc2_b,
    const float* __restrict__ fc3_w, const float* __restrict__ fc3_b,
    const __hip_bfloat16* __restrict__ wbf_hh0,
    const __hip_bfloat16* __restrict__ wcat1,
    __hip_bfloat16* h0, __hip_bfloat16* h1,
    float* __restrict__ partial, int* bar, float* __restrict__ out)
{
    const int layer = blockIdx.x >> 7;
    const int bid = blockIdx.x & 127;
    const int bb = bid >> 4, jb = bid & 15;
    const int b0i = bb * 32, j0 = jb * 32;
    const int tid = threadIdx.x, lane = tid & 63, g = tid >> 6;
    const int lrow = lane & 15, lgrp = lane >> 4;
    const int koff = lgrp * 8;

    __shared__ float gl[4][32][33];
    __shared__ float wih_s[4][32][INc];
    __shared__ float bias_s[4][32];

    {
        const float* bsrc = (layer == 0) ? b0v : b1v;
        for (int idx = tid; idx < 128; idx += 256) {
            int gg = idx >> 5, jl = idx & 31;
            bias_s[gg][jl] = bsrc[gg * Hc + j0 + jl];
        }
        if (layer == 0) {
            for (int idx = tid; idx < 4 * 32 * INc; idx += 256) {
                int gg = idx / (32 * INc), r = idx % (32 * INc);
                int jl = r / INc, d = r % INc;
                wih_s[gg][jl][d] = w_ih0[(size_t)(gg * Hc + j0 + jl) * INc + d];
            }
        }
    }
    __syncthreads();

    const int bl = tid >> 3, j4 = tid & 7;   // epilogue: (batch-in-tile, j-group of 4)
    const int b = b0i + bl;
    float c_r[4] = {0.f, 0.f, 0.f, 0.f};

    if (layer == 0) {
        bf16x8 wr0[16], wr1[16];
        {
            const bf16x8* p0 = reinterpret_cast<const bf16x8*>(
                wbf_hh0 + (size_t)(g * Hc + j0 + lrow) * Hc + koff);
            const bf16x8* p1 = reinterpret_cast<const bf16x8*>(
                wbf_hh0 + (size_t)(g * Hc + j0 + 16 + lrow) * Hc + koff);
#pragma unroll
            for (int kk = 0; kk < 16; kk++) { wr0[kk] = p0[kk * 4]; wr1[kk] = p1[kk * 4]; }
        }
        for (int i = 0; i <= Tc; i++) {
            if (i < Tc) {
                const __hip_bfloat16* h0r = h0 + (size_t)(i & 1) * BH;
                __hip_bfloat16* h0w = h0 + (size_t)((i & 1) ^ 1) * BH;
                // hoist x loads so MFMA covers their latency
                float xv[INc];
#pragma unroll
                for (int d = 0; d < INc; d++)
                    xv[d] = x_time[((size_t)b * Tc + i) * INc + d];

                f32x4 a00 = {0,0,0,0}, a01 = {0,0,0,0}, a10 = {0,0,0,0}, a11 = {0,0,0,0};
                const bf16x8* pa0 = reinterpret_cast<const bf16x8*>(
                    h0r + (size_t)(b0i + lrow) * Hc + koff);
                const bf16x8* pa1 = reinterpret_cast<const bf16x8*>(
                    h0r + (size_t)(b0i + 16 + lrow) * Hc + koff);
#pragma unroll
                for (int kk = 0; kk < 16; kk++) {
                    bf16x8 A0 = pa0[kk * 4], A1 = pa1[kk * 4];
                    a00 = __builtin_amdgcn_mfma_f32_16x16x32_bf16(A0, wr0[kk], a00, 0, 0, 0);
                    a01 = __builtin_amdgcn_mfma_f32_16x16x32_bf16(A0, wr1[kk], a01, 0, 0, 0);
                    a10 = __builtin_amdgcn_mfma_f32_16x16x32_bf16(A1, wr0[kk], a10, 0, 0, 0);
                    a11 = __builtin_amdgcn_mfma_f32_16x16x32_bf16(A1, wr1[kk], a11, 0, 0, 0);
                }
#pragma unroll
                for (int r = 0; r < 4; r++) {
                    gl[g][lgrp * 4 + r][lrow]          = a00[r];
                    gl[g][lgrp * 4 + r][16 + lrow]     = a01[r];
                    gl[g][16 + lgrp * 4 + r][lrow]     = a10[r];
                    gl[g][16 + lgrp * 4 + r][16 + lrow] = a11[r];
                }
                __syncthreads();

                unsigned int pk0 = 0, pk1 = 0;
#pragma unroll
                for (int jj = 0; jj < 4; jj++) {
                    const int jl = j4 * 4 + jj;
                    float pre[4];
#pragma unroll
                    for (int gg = 0; gg < 4; gg++) {
                        float s = gl[gg][bl][jl] + bias_s[gg][jl];
#pragma unroll
                        for (int d = 0; d < INc; d++) s = fmaf(xv[d], wih_s[gg][jl][d], s);
                        pre[gg] = s;
                    }
                    float ig = sigmoidf_(pre[0]), fg = sigmoidf_(pre[1]);
                    float gv = tanhf_(pre[2]), og = sigmoidf_(pre[3]);
                    float c = fg * c_r[jj] + ig * gv;
                    c_r[jj] = c;
                    float h = og * tanhf_(c);
                    unsigned int hb = bfbits(h);
                    if (jj == 0) pk0 = hb;
                    else if (jj == 1) pk0 |= hb << 16;
                    else if (jj == 2) pk1 = hb;
                    else pk1 |= hb << 16;
                }
                *reinterpret_cast<uint2*>(h0w + (size_t)b * Hc + j0 + j4 * 4) =
                    make_uint2(pk0, pk1);
            }
            gbar(bar, i + 1, tid);
        }
        gbar(bar, Tc + 2, tid);
        if (blockIdx.x == 0) {
            float t0s = fc1_b[0], t1s = fc1_b[1];
            for (int jg = 0; jg < 16; jg++) {
                t0s += partial[((size_t)jg * Bc + tid) * 2 + 0];
                t1s += partial[((size_t)jg * Bc + tid) * 2 + 1];
            }
            float s0 = fc2_b[0] + x_stat[tid * 3 + 0] * fc2_w[0] + x_stat[tid * 3 + 1] * fc2_w[1] + x_stat[tid * 3 + 2] * fc2_w[2];
            float s1 = fc2_b[1] + x_stat[tid * 3 + 0] * fc2_w[3] + x_stat[tid * 3 + 1] * fc2_w[4] + x_stat[tid * 3 + 2] * fc2_w[5];
            out[tid * 2 + 0] = fc3_b[0] + fc3_w[0] * s0 + fc3_w[1] * s1 + fc3_w[2] * t0s + fc3_w[3] * t1s;
            out[tid * 2 + 1] = fc3_b[1] + fc3_w[4] * s0 + fc3_w[5] * s1 + fc3_w[6] * t0s + fc3_w[7] * t1s;
        }
    } else {
        bf16x8 wr0[32], wr1[32];
        {
            const bf16x8* p0 = reinterpret_cast<const bf16x8*>(
                wcat1 + (size_t)(g * Hc + j0 + lrow) * 1024 + koff);
            const bf16x8* p1 = reinterpret_cast<const bf16x8*>(
                wcat1 + (size_t)(g * Hc + j0 + 16 + lrow) * 1024 + koff);
#pragma unroll
            for (int kk = 0; kk < 32; kk++) { wr0[kk] = p0[kk * 4]; wr1[kk] = p1[kk * 4]; }
        }
        float v0 = 0.f, v1 = 0.f;
        for (int i = 0; i <= Tc; i++) {
            if (i >= 1) {
                const int t1 = i - 1;
                const __hip_bfloat16* h1r = h1 + (size_t)((i & 1) ^ 1) * BH;
                __hip_bfloat16* h1w = h1 + (size_t)(i & 1) * BH;
                const __hip_bfloat16* h0r = h0 + (size_t)(i & 1) * BH;
                // hoist fc1 weight loads
                float wf0[4], wf1[4];
                {
                    const float* fp = fc1_w + (size_t)t1 * Hc + j0 + j4 * 4;
#pragma unroll
                    for (int jj = 0; jj < 4; jj++) {
                        wf0[jj] = fp[jj];
                        wf1[jj] = fp[(size_t)Tc * Hc + jj];
                    }
                }
                f32x4 a00 = {0,0,0,0}, a01 = {0,0,0,0}, a10 = {0,0,0,0}, a11 = {0,0,0,0};
                const bf16x8* pa0 = reinterpret_cast<const bf16x8*>(
                    h1r + (size_t)(b0i + lrow) * Hc + koff);
                const bf16x8* pa1 = reinterpret_cast<const bf16x8*>(
                    h1r + (size_t)(b0i + 16 + lrow) * Hc + koff);
                const bf16x8* pc0 = reinterpret_cast<const bf16x8*>(
                    h0r + (size_t)(b0i + lrow) * Hc + koff);
                const bf16x8* pc1 = reinterpret_cast<const bf16x8*>(
                    h0r + (size_t)(b0i + 16 + lrow) * Hc + koff);
#pragma unroll
                for (int kk = 0; kk < 32; kk++) {
                    bf16x8 A0 = (kk < 16) ? pa0[kk * 4] : pc0[(kk - 16) * 4];
                    bf16x8 A1 = (kk < 16) ? pa1[kk * 4] : pc1[(kk - 16) * 4];
                    a00 = __builtin_amdgcn_mfma_f32_16x16x32_bf16(A0, wr0[kk], a00, 0, 0, 0);
                    a01 = __builtin_amdgcn_mfma_f32_16x16x32_bf16(A0, wr1[kk], a01, 0, 0, 0);
                    a10 = __builtin_amdgcn_mfma_f32_16x16x32_bf16(A1, wr0[kk], a10, 0, 0, 0);
                    a11 = __builtin_amdgcn_mfma_f32_16x16x32_bf16(A1, wr1[kk], a11, 0, 0, 0);
                }
#pragma unroll
                for (int r = 0; r < 4; r++) {
                    gl[g][lgrp * 4 + r][lrow]          = a00[r];
                    gl[g][lgrp * 4 + r][16 + lrow]     = a01[r];
                    gl[g][16 + lgrp * 4 + r][lrow]     = a10[r];
                    gl[g][16 + lgrp * 4 + r][16 + lrow] = a11[r];
                }
                __syncthreads();

                unsigned int pk0 = 0, pk1 = 0;
#pragma unroll
                for (int jj = 0; jj < 4; jj++) {
                    const int jl = j4 * 4 + jj;
                    float pre[4];
#pragma unroll
                    for (int gg = 0; gg < 4; gg++)
                        pre[gg] = gl[gg][bl][jl] + bias_s[gg][jl];
                    float ig = sigmoidf_(pre[0]), fg = sigmoidf_(pre[1]);
                    float gv = tanhf_(pre[2]), og = sigmoidf_(pre[3]);
                    float c = fg * c_r[jj] + ig * gv;
                    c_r[jj] = c;
                    float h = og * tanhf_(c);
                    v0 = fmaf(h, wf0[jj], v0);
                    v1 = fmaf(h, wf1[jj], v1);
                    unsigned int hb = bfbits(h);
                    if (jj == 0) pk0 = hb;
                    else if (jj == 1) pk0 |= hb << 16;
                    else if (jj == 2) pk1 = hb;
                    else pk1 |= hb << 16;
                }
                *reinterpret_cast<uint2*>(h1w + (size_t)b * Hc + j0 + j4 * 4) =
                    make_uint2(pk0, pk1);
            }
            gbar(bar, i + 1, tid);
        }
        // reduce fc1 partials across the 8 j4 threads of each batch row, write once
#pragma unroll
        for (int off = 1; off < 8; off <<= 1) {
            v0 += __shfl_xor(v0, off);
            v1 += __shfl_xor(v1, off);
        }
        if (j4 == 0) {
            partial[((size_t)jb * Bc + b) * 2 + 0] = v0;
            partial[((size_t)jb * Bc + b) * 2 + 1] = v1;
        }
        gbar(bar, Tc + 2, tid);
    }
}

__global__ void convert_weights(const float* __restrict__ w_hh0,
                                const float* __restrict__ w_hh1,
                                const float* __restrict__ w_ih1,
                                __hip_bfloat16* __restrict__ o_hh0,
                                __hip_bfloat16* __restrict__ o_cat)
{
    const int i = blockIdx.x * 256 + threadIdx.x;  // 4096*256 = 2048*512
    o_hh0[i] = __float2bfloat16(w_hh0[i]);
    const int r = i >> 9, k = i & 511;
    o_cat[(size_t)r * 1024 + k] = __float2bfloat16(w_hh1[i]);
    o_cat[(size_t)r * 1024 + 512 + k] = __float2bfloat16(w_ih1[i]);
}

extern "C" void kernel_launch(void* const* d_in, const int* in_sizes, int n_in,
                              void* d_out, int out_size, void* d_ws, size_t ws_size,
                              hipStream_t stream)
{
    const float* x_time = (const float*)d_in[0];
    const float* x_stat = (const float*)d_in[1];
    const float* w_ih0 = (const float*)d_in[2];
    const float* w_hh0 = (const float*)d_in[3];
    const float* b0    = (const float*)d_in[4];
    const float* w_ih1 = (const float*)d_in[5];
    const float* w_hh1 = (const float*)d_in[6];
    const float* b1    = (const float*)d_in[7];
    const float* fc1_w = (const float*)d_in[8];
    const float* fc1_b = (const float*)d_in[9];
    const float* fc2_w = (const float*)d_in[10];
    const float* fc2_b = (const float*)d_in[11];
    const float* fc3_w = (const float*)d_in[12];
    const float* fc3_b = (const float*)d_in[13];

    __hip_bfloat16* wbf_hh0 = (__hip_bfloat16*)d_ws;                 // 2048*512
    __hip_bfloat16* wcat1 = wbf_hh0 + (size_t)2048 * 512;            // 2048*1024
    __hip_bfloat16* h0p = wcat1 + (size_t)2048 * 1024;               // 2*BH
    __hip_bfloat16* h1p = h0p + (size_t)2 * BH;                      // 2*BH
    float* partialp = (float*)(h1p + (size_t)2 * BH);                // 16*256*2
    int* barp = (int*)(partialp + (size_t)16 * Bc * 2);

    // zero h0,h1 (bf16), partial, barrier counter
    const size_t zoff = ((size_t)2048 * 512 + (size_t)2048 * 1024) * sizeof(__hip_bfloat16);
    const size_t zlen = (size_t)4 * BH * sizeof(__hip_bfloat16)
                      + (size_t)16 * Bc * 2 * sizeof(float) + 256;
    hipMemsetAsync((char*)d_ws + zoff, 0, zlen, stream);

    convert_weights<<<4096, 256, 0, stream>>>(w_hh0, w_hh1, w_ih1, wbf_hh0, wcat1);

    lstm_persist<<<NB, 256, 0, stream>>>(
        x_time, w_ih0, b0, b1, fc1_w, fc1_b, x_stat,
        fc2_w, fc2_b, fc3_w, fc3_b,
        wbf_hh0, wcat1, h0p, h1p, partialp, barp, (float*)d_out);
}